// Round 1
// baseline (428.413 us; speedup 1.0000x reference)
//
#include <hip/hip_runtime.h>

#define BATCH 8
#define SEQ   2048
#define DIM   768
#define VOCAB 50257

// out[b][s][d] = W_emb[d * VOCAB + tokens[b][s]] + W_pos[s][d]
//
// Block = 192 threads (3 waves), one block per (b,s) pair.
// Thread i handles d = 4*i .. 4*i+3 (DIM = 768 = 192*4).
//   - W_pos read and out write: float4, fully coalesced (16 B/lane).
//   - W_emb reads: 4 scalar loads at stride VOCAB (column gather — layout-imposed).
// Block order: s-major, b-minor so the 8 blocks sharing a W_pos row run
// back-to-back (L2 reuse of the positional row).
__global__ __launch_bounds__(192) void emb_pos_kernel(
    const int*   __restrict__ tokens,
    const float* __restrict__ W_emb,
    const float* __restrict__ W_pos,
    float*       __restrict__ out)
{
    const int bid = blockIdx.x;        // 0 .. BATCH*SEQ-1
    const int s   = bid >> 3;          // bid / BATCH
    const int b   = bid & 7;           // bid % BATCH
    const int t   = tokens[b * SEQ + s];   // block-uniform -> scalar broadcast

    const int d = threadIdx.x * 4;     // 0, 4, ..., 764

    const float* we = W_emb + (size_t)d * VOCAB + t;
    const float4 p  = *reinterpret_cast<const float4*>(W_pos + s * DIM + d);

    float4 r;
    r.x = we[0]                   + p.x;
    r.y = we[(size_t)VOCAB]       + p.y;
    r.z = we[(size_t)2 * VOCAB]   + p.z;
    r.w = we[(size_t)3 * VOCAB]   + p.w;

    *reinterpret_cast<float4*>(out + ((size_t)b * SEQ + s) * DIM + d) = r;
}

extern "C" void kernel_launch(void* const* d_in, const int* in_sizes, int n_in,
                              void* d_out, int out_size, void* d_ws, size_t ws_size,
                              hipStream_t stream) {
    const int*   tokens = (const int*)  d_in[0];
    const float* W_emb  = (const float*)d_in[1];
    const float* W_pos  = (const float*)d_in[2];
    float*       out    = (float*)d_out;

    emb_pos_kernel<<<dim3(BATCH * SEQ), dim3(192), 0, stream>>>(tokens, W_emb, W_pos, out);
}

// Round 7
// 294.822 us; speedup vs baseline: 1.4531x; 1.4531x over previous
//
#include <hip/hip_runtime.h>

#define BATCH 8
#define SEQ   2048
#define DIM   768
#define VOCAB 50257
#define NTOK  (BATCH * SEQ)        // 16384
#define NBUCKET 3142               // ceil(VOCAB / 16) -- one bucket per 64B line-column
#define SORT_THREADS 1024

typedef float f32x4 __attribute__((ext_vector_type(4)));

// ---------------------------------------------------------------------------
// Kernel 1: counting-sort the 16384 (token, flat_pos) pairs by token line-id
// (t >> 4). Single block. Output: ws[j] = (t << 14) | flat_pos, sorted by t>>4.
// flat_pos = b*SEQ + s fits in 14 bits (16384). t < 50257 fits in 16 bits.
// ---------------------------------------------------------------------------
__global__ __launch_bounds__(SORT_THREADS) void sort_tokens_kernel(
    const int* __restrict__ tokens, unsigned* __restrict__ ws)
{
    __shared__ unsigned cnt[4096];   // NBUCKET=3142, padded to 4*1024
    __shared__ unsigned wsum[16];
    const int tid = threadIdx.x;

    for (int j = tid; j < 4096; j += SORT_THREADS) cnt[j] = 0;
    __syncthreads();

    // histogram of line-ids
    for (int i = tid; i < NTOK; i += SORT_THREADS) {
        int t = tokens[i];
        atomicAdd(&cnt[t >> 4], 1u);
    }
    __syncthreads();

    // exclusive prefix sum over 4096 buckets: 4 buckets per thread
    unsigned c0 = cnt[4*tid+0], c1 = cnt[4*tid+1], c2 = cnt[4*tid+2], c3 = cnt[4*tid+3];
    unsigned tsum = c0 + c1 + c2 + c3;
    unsigned x = tsum;                        // inclusive wave scan (64 lanes)
    for (int off = 1; off < 64; off <<= 1) {
        unsigned y = __shfl_up(x, off, 64);
        if ((tid & 63) >= off) x += y;
    }
    if ((tid & 63) == 63) wsum[tid >> 6] = x; // wave totals (16 waves)
    __syncthreads();
    if (tid < 16) {                           // scan the 16 wave totals
        unsigned w = wsum[tid];
        for (int off = 1; off < 16; off <<= 1) {
            unsigned y = __shfl_up(w, off, 64);
            if (tid >= off) w += y;
        }
        wsum[tid] = w;                        // inclusive
    }
    __syncthreads();
    unsigned wavebase = (tid >= 64) ? wsum[(tid >> 6) - 1] : 0u;
    unsigned excl = wavebase + x - tsum;      // global exclusive offset of this thread's 4 buckets
    cnt[4*tid+0] = excl;
    cnt[4*tid+1] = excl + c0;
    cnt[4*tid+2] = excl + c0 + c1;
    cnt[4*tid+3] = excl + c0 + c1 + c2;
    __syncthreads();

    // scatter in sorted order
    for (int i = tid; i < NTOK; i += SORT_THREADS) {
        int t = tokens[i];
        unsigned p = atomicAdd(&cnt[t >> 4], 1u);
        ws[p] = ((unsigned)t << 14) | (unsigned)i;
    }
}

// ---------------------------------------------------------------------------
// Kernel 2: gather + positional add over SORTED token order.
// Block b -> sorted index ((b&7)<<11) | (b>>3): XCD x (round-robin bid%8)
// processes the contiguous sorted range [x*2048, (x+1)*2048) in dispatch
// order -> same-line tokens hit the same XCD's L2 back-to-back.
// 192 threads, thread i handles d = 4i..4i+3.
// ---------------------------------------------------------------------------
__global__ __launch_bounds__(192) void emb_pos_kernel(
    const unsigned* __restrict__ ws,
    const float*    __restrict__ W_emb,
    const float*    __restrict__ W_pos,
    float*          __restrict__ out)
{
    const int bid  = blockIdx.x;
    const int sidx = ((bid & 7) << 11) | (bid >> 3);   // XCD-partitioned sorted order
    const unsigned packed = ws[sidx];                  // block-uniform
    const int t = (int)(packed >> 14);
    const int i = (int)(packed & 16383u);              // flat b*SEQ+s
    const int s = i & (SEQ - 1);

    const int d = threadIdx.x * 4;

    const float* we = W_emb + (size_t)d * VOCAB + t;
    const f32x4 p  = *reinterpret_cast<const f32x4*>(W_pos + s * DIM + d);

    f32x4 r;
    r.x = we[0]                 + p.x;
    r.y = we[(size_t)VOCAB]     + p.y;
    r.z = we[(size_t)2 * VOCAB] + p.z;
    r.w = we[(size_t)3 * VOCAB] + p.w;

    // streaming store: never re-read, keep L2 for the gather window
    __builtin_nontemporal_store(r, reinterpret_cast<f32x4*>(out + (size_t)i * DIM + d));
}

extern "C" void kernel_launch(void* const* d_in, const int* in_sizes, int n_in,
                              void* d_out, int out_size, void* d_ws, size_t ws_size,
                              hipStream_t stream) {
    const int*   tokens = (const int*)  d_in[0];
    const float* W_emb  = (const float*)d_in[1];
    const float* W_pos  = (const float*)d_in[2];
    float*       out    = (float*)d_out;
    unsigned*    ws     = (unsigned*)d_ws;             // needs 16384 * 4 B = 64 KiB

    sort_tokens_kernel<<<dim3(1), dim3(SORT_THREADS), 0, stream>>>(tokens, ws);
    emb_pos_kernel<<<dim3(NTOK), dim3(192), 0, stream>>>(ws, W_emb, W_pos, out);
}

// Round 8
// 270.597 us; speedup vs baseline: 1.5832x; 1.0895x over previous
//
#include <hip/hip_runtime.h>

#define BATCH 8
#define SEQ   2048
#define DIM   768
#define VOCAB 50257
#define NTOK  (BATCH * SEQ)        // 16384
#define NBUCKET 3142               // ceil(VOCAB/16): one bucket per 64B line-column
#define OFF_BASE NTOK              // ws[NTOK .. NTOK+4096): bucket start offsets
#define SORT_THREADS 1024
#define LDS_PITCH 772              // 768 + 4 pad words (bank-spread for transposed writes)

typedef float f32x4 __attribute__((ext_vector_type(4)));

// ---------------------------------------------------------------------------
// Kernel 1: counting-sort the 16384 (token, flat_pos) pairs by bucket (t>>4).
// Also dumps the exclusive bucket-start offsets to ws[OFF_BASE..OFF_BASE+4096).
// ws[j] = (t << 14) | flat_pos for the sorted stream.
// ---------------------------------------------------------------------------
__global__ __launch_bounds__(SORT_THREADS) void sort_tokens_kernel(
    const int* __restrict__ tokens, unsigned* __restrict__ ws)
{
    __shared__ unsigned cnt[4096];   // NBUCKET=3142, padded to 4096
    __shared__ unsigned wsum[16];
    const int tid = threadIdx.x;

    for (int j = tid; j < 4096; j += SORT_THREADS) cnt[j] = 0;
    __syncthreads();

    // histogram of bucket ids
    for (int i = tid; i < NTOK; i += SORT_THREADS) {
        int t = tokens[i];
        atomicAdd(&cnt[t >> 4], 1u);
    }
    __syncthreads();

    // exclusive prefix sum over 4096 buckets: 4 buckets per thread
    unsigned c0 = cnt[4*tid+0], c1 = cnt[4*tid+1], c2 = cnt[4*tid+2], c3 = cnt[4*tid+3];
    unsigned tsum = c0 + c1 + c2 + c3;
    unsigned x = tsum;                        // inclusive wave scan (64 lanes)
    for (int off = 1; off < 64; off <<= 1) {
        unsigned y = __shfl_up(x, off, 64);
        if ((tid & 63) >= off) x += y;
    }
    if ((tid & 63) == 63) wsum[tid >> 6] = x; // wave totals (16 waves)
    __syncthreads();
    if (tid < 16) {                           // scan the 16 wave totals
        unsigned w = wsum[tid];
        for (int off = 1; off < 16; off <<= 1) {
            unsigned y = __shfl_up(w, off, 64);
            if (tid >= off) w += y;
        }
        wsum[tid] = w;                        // inclusive
    }
    __syncthreads();
    unsigned wavebase = (tid >= 64) ? wsum[(tid >> 6) - 1] : 0u;
    unsigned excl = wavebase + x - tsum;      // global exclusive offset of this thread's buckets
    cnt[4*tid+0] = excl;
    cnt[4*tid+1] = excl + c0;
    cnt[4*tid+2] = excl + c0 + c1;
    cnt[4*tid+3] = excl + c0 + c1 + c2;
    __syncthreads();

    // dump bucket offsets BEFORE the scatter mutates cnt.
    // Buckets >= NBUCKET are empty -> their exclusive prefix == NTOK, which
    // gives the sentinel off[NBUCKET] = NTOK for free.
    for (int j = tid; j < 4096; j += SORT_THREADS) ws[OFF_BASE + j] = cnt[j];
    __syncthreads();

    // scatter in sorted order
    for (int i = tid; i < NTOK; i += SORT_THREADS) {
        int t = tokens[i];
        unsigned p = atomicAdd(&cnt[t >> 4], 1u);
        ws[p] = ((unsigned)t << 14) | (unsigned)i;
    }
}

// ---------------------------------------------------------------------------
// Kernel 2: one block per bucket. Stream the bucket's 768x16 W_emb slab
// coalesced (each 64B line-segment read exactly once), transpose into LDS,
// then emit every token of the bucket: out[i,:] = slab[:, t-base] + W_pos[s,:].
//
//   staging : thread tid -> row r = (tid>>2) + it*64, quarter q = tid&3;
//             reads f32x4 W_emb[r*VOCAB + base + 4q] (16 fully-used lines per
//             wave instruction). LDS write transposed: slab[col][row], pitch
//             772 words -> per-instr banks (16q + r + 4k) % 32 = 2-way (free).
//   emission: threads 0..191, thread tid owns d = 4*tid..4*tid+3;
//             slab read = stride-1 ds_read_b128 (conflict-free), W_pos read
//             and out write coalesced f32x4; nontemporal store (never re-read).
// ---------------------------------------------------------------------------
__global__ __launch_bounds__(256) void emb_slab_kernel(
    const unsigned* __restrict__ ws,
    const float*    __restrict__ W_emb,
    const float*    __restrict__ W_pos,
    float*          __restrict__ out)
{
    __shared__ float slab[16 * LDS_PITCH];   // 49,408 B

    const int c = blockIdx.x;                // bucket id, 0..NBUCKET-1
    const unsigned start = ws[OFF_BASE + c];
    const unsigned end   = ws[OFF_BASE + c + 1];
    if (start == end) return;                // empty bucket (~0.5%)

    // clamp so the last (partial) bucket's slab stays inside the table;
    // its tokens use column j = t - base (= 15 for the single valid token).
    const int base = (16 * c <= VOCAB - 16) ? 16 * c : (VOCAB - 16);

    const int tid = threadIdx.x;
    const int q  = tid & 3;                  // which f32x4 of the 16-float row
    const int r0 = tid >> 2;                 // row 0..63

    // ---- stage: 12 iterations x 64 rows; loads first (all in flight), then LDS
    f32x4 v[12];
    #pragma unroll
    for (int it = 0; it < 12; ++it) {
        const int r = r0 + it * 64;
        v[it] = *reinterpret_cast<const f32x4*>(W_emb + (size_t)r * VOCAB + base + 4 * q);
    }
    #pragma unroll
    for (int it = 0; it < 12; ++it) {
        const int r = r0 + it * 64;
        slab[(4*q + 0) * LDS_PITCH + r] = v[it].x;
        slab[(4*q + 1) * LDS_PITCH + r] = v[it].y;
        slab[(4*q + 2) * LDS_PITCH + r] = v[it].z;
        slab[(4*q + 3) * LDS_PITCH + r] = v[it].w;
    }
    __syncthreads();

    // ---- emission: one loop iteration per token in the bucket
    if (tid < 192) {
        const int d4 = tid * 4;
        for (unsigned idx = start; idx < end; ++idx) {
            const unsigned packed = ws[idx];           // block-uniform -> s_load
            const int t = (int)(packed >> 14);
            const int i = (int)(packed & 16383u);      // flat b*SEQ+s
            const int s = i & (SEQ - 1);
            const int j = t - base;

            const f32x4 col = *reinterpret_cast<const f32x4*>(&slab[j * LDS_PITCH + d4]);
            const f32x4 p   = *reinterpret_cast<const f32x4*>(W_pos + s * DIM + d4);
            const f32x4 rr  = col + p;
            __builtin_nontemporal_store(rr, reinterpret_cast<f32x4*>(out + (size_t)i * DIM + d4));
        }
    }
}

extern "C" void kernel_launch(void* const* d_in, const int* in_sizes, int n_in,
                              void* d_out, int out_size, void* d_ws, size_t ws_size,
                              hipStream_t stream) {
    const int*   tokens = (const int*)  d_in[0];
    const float* W_emb  = (const float*)d_in[1];
    const float* W_pos  = (const float*)d_in[2];
    float*       out    = (float*)d_out;
    unsigned*    ws     = (unsigned*)d_ws;   // needs (16384 + 4096) * 4 B = 80 KiB

    sort_tokens_kernel<<<dim3(1), dim3(SORT_THREADS), 0, stream>>>(tokens, ws);
    emb_slab_kernel<<<dim3(NBUCKET), dim3(256), 0, stream>>>(ws, W_emb, W_pos, out);
}

// Round 10
// 269.415 us; speedup vs baseline: 1.5902x; 1.0044x over previous
//
#include <hip/hip_runtime.h>

#define BATCH 8
#define SEQ   2048
#define DIM   768
#define VOCAB 50257
#define NTOK  (BATCH * SEQ)        // 16384
#define NBUCKET 3142               // ceil(VOCAB/16): one bucket per 64B line-column
#define NGROUP  393                // ceil(NBUCKET/8): 8 buckets = 128 cols per group
#define OFF_BASE NTOK              // ws[NTOK .. NTOK+4096): bucket start offsets
#define SORT_THREADS 1024
#define PCOLS 128                  // panel columns (vocab dim)
#define PROWS 96                   // panel rows (emb dim) = 768/8 row-chunks

typedef float f32x4 __attribute__((ext_vector_type(4)));

// ---------------------------------------------------------------------------
// Kernel 1: counting-sort the 16384 (token, flat_pos) pairs by bucket (t>>4).
// Dumps exclusive bucket-start offsets to ws[OFF_BASE..OFF_BASE+4096).
// ws[j] = (t << 14) | flat_pos for the sorted stream.
// ---------------------------------------------------------------------------
__global__ __launch_bounds__(SORT_THREADS) void sort_tokens_kernel(
    const int* __restrict__ tokens, unsigned* __restrict__ ws)
{
    __shared__ unsigned cnt[4096];
    __shared__ unsigned wsum[16];
    const int tid = threadIdx.x;

    for (int j = tid; j < 4096; j += SORT_THREADS) cnt[j] = 0;
    __syncthreads();

    for (int i = tid; i < NTOK; i += SORT_THREADS) {
        int t = tokens[i];
        atomicAdd(&cnt[t >> 4], 1u);
    }
    __syncthreads();

    unsigned c0 = cnt[4*tid+0], c1 = cnt[4*tid+1], c2 = cnt[4*tid+2], c3 = cnt[4*tid+3];
    unsigned tsum = c0 + c1 + c2 + c3;
    unsigned x = tsum;
    for (int off = 1; off < 64; off <<= 1) {
        unsigned y = __shfl_up(x, off, 64);
        if ((tid & 63) >= off) x += y;
    }
    if ((tid & 63) == 63) wsum[tid >> 6] = x;
    __syncthreads();
    if (tid < 16) {
        unsigned w = wsum[tid];
        for (int off = 1; off < 16; off <<= 1) {
            unsigned y = __shfl_up(w, off, 64);
            if (tid >= off) w += y;
        }
        wsum[tid] = w;
    }
    __syncthreads();
    unsigned wavebase = (tid >= 64) ? wsum[(tid >> 6) - 1] : 0u;
    unsigned excl = wavebase + x - tsum;
    cnt[4*tid+0] = excl;
    cnt[4*tid+1] = excl + c0;
    cnt[4*tid+2] = excl + c0 + c1;
    cnt[4*tid+3] = excl + c0 + c1 + c2;
    __syncthreads();

    // dump offsets before scatter mutates cnt; empty tail buckets give the
    // sentinel off[k] = NTOK for free.
    for (int j = tid; j < 4096; j += SORT_THREADS) ws[OFF_BASE + j] = cnt[j];
    __syncthreads();

    for (int i = tid; i < NTOK; i += SORT_THREADS) {
        int t = tokens[i];
        unsigned p = atomicAdd(&cnt[t >> 4], 1u);
        ws[p] = ((unsigned)t << 14) | (unsigned)i;
    }
}

// ---------------------------------------------------------------------------
// Kernel 2: panel kernel. Block b = (group G = b>>3, row-chunk rc = b&7).
// Group G covers vocab cols [128G, 128G+128) (8 buckets); chunk rc covers
// emb rows [96rc, 96rc+96). Stage the 96x128 panel into LDS with 512B
// contiguous spans per row (2 spans per wave instruction -> DRAM streaming),
// then emit the group's tokens: out[i, rbase+d] = slab[d][t-cbase] + W_pos.
//
// LDS layout: row-major slab[row][col ^ ((row>>2 & 7)<<2)] — b128 writes stay
// contiguous per row (conflict-free); emission column b32 reads spread over
// 8 banks (~3-way, free-ish).
// Emission: flat u = token*24 + lane; all 256 threads active, ~10 tokens in
// parallel; f32x4 W_pos reads / out writes, nontemporal stores.
// ---------------------------------------------------------------------------
__global__ __launch_bounds__(256) void emb_panel_kernel(
    const unsigned* __restrict__ ws,
    const float*    __restrict__ W_emb,
    const float*    __restrict__ W_pos,
    float*          __restrict__ out)
{
    __shared__ float slab[PROWS * PCOLS];   // 48 KiB -> 3 blocks/CU

    const int b  = blockIdx.x;
    const int G  = b >> 3;                  // group 0..392
    const int rc = b & 7;                   // row chunk 0..7
    const unsigned start = ws[OFF_BASE + G * 8];
    const unsigned end   = ws[OFF_BASE + G * 8 + 8];
    if (start == end) return;               // (essentially never at lambda~42)

    const int cbase = G * PCOLS;            // 0, 128, ..., 50176
    const int rbase = rc * PROWS;
    const int tid   = threadIdx.x;

    // ---- stage: 12 x f32x4 per thread; loads all issued, then LDS writes
    f32x4 v[12];
    #pragma unroll
    for (int it = 0; it < 12; ++it) {
        const int f   = it * 1024 + tid * 4;
        const int row = f >> 7;             // 0..95
        const int col = f & 127;
        const int gcol = cbase + col;
        const float* src = W_emb + (size_t)(rbase + row) * VOCAB + gcol;
        if (gcol + 4 <= VOCAB) {            // uniform-true except last group
            v[it] = *reinterpret_cast<const f32x4*>(src);
        } else {
            f32x4 tmp = {0.f, 0.f, 0.f, 0.f};
            #pragma unroll
            for (int k = 0; k < 4; ++k)
                if (gcol + k < VOCAB) tmp[k] = src[k];
            v[it] = tmp;
        }
    }
    #pragma unroll
    for (int it = 0; it < 12; ++it) {
        const int f   = it * 1024 + tid * 4;
        const int row = f >> 7;
        const int col = f & 127;
        const int colx = col ^ (((row >> 2) & 7) << 2);   // XOR bank swizzle
        *reinterpret_cast<f32x4*>(&slab[row * PCOLS + colx]) = v[it];
    }
    __syncthreads();

    // ---- emission: flat work = ntok * 24 f32x4-lanes (96 floats/token here)
    const int ntok = (int)(end - start);
    const int U = ntok * 24;
    for (int u = tid; u < U; u += 256) {
        const int tok = u / 24;
        const int lp  = u - tok * 24;
        const unsigned packed = ws[start + tok];
        const int t = (int)(packed >> 14);
        const int i = (int)(packed & 16383u);   // flat b*SEQ+s
        const int s = i & (SEQ - 1);
        const int j = t - cbase;                // 0..127
        const int d0 = lp * 4;                  // 0..92

        float e[4];
        #pragma unroll
        for (int k = 0; k < 4; ++k) {
            const int row = d0 + k;
            e[k] = slab[row * PCOLS + (j ^ (((row >> 2) & 7) << 2))];
        }
        const f32x4 p = *reinterpret_cast<const f32x4*>(
            W_pos + (size_t)s * DIM + rbase + d0);
        f32x4 rr;
        rr.x = e[0] + p.x; rr.y = e[1] + p.y; rr.z = e[2] + p.z; rr.w = e[3] + p.w;
        __builtin_nontemporal_store(rr,
            reinterpret_cast<f32x4*>(out + (size_t)i * DIM + rbase + d0));
    }
}

extern "C" void kernel_launch(void* const* d_in, const int* in_sizes, int n_in,
                              void* d_out, int out_size, void* d_ws, size_t ws_size,
                              hipStream_t stream) {
    const int*   tokens = (const int*)  d_in[0];
    const float* W_emb  = (const float*)d_in[1];
    const float* W_pos  = (const float*)d_in[2];
    float*       out    = (float*)d_out;
    unsigned*    ws     = (unsigned*)d_ws;   // (16384 + 4096) * 4 B = 80 KiB

    sort_tokens_kernel<<<dim3(1), dim3(SORT_THREADS), 0, stream>>>(tokens, ws);
    emb_panel_kernel<<<dim3(NGROUP * 8), dim3(256), 0, stream>>>(ws, W_emb, W_pos, out);
}